// Round 4
// baseline (703.776 us; speedup 1.0000x reference)
//
#include <hip/hip_runtime.h>
#include <hip/hip_bf16.h>

// GraphSageLayer on MI355X. B=4, N=4096, D_IN=REP=D_OUT=128.
// proj (nodes->3 reps, bf16) -> agg (adj @ in_rep, adj^T @ out_rep) -> final (concat @ W_upd^T, tanh).
//
// R4: back to R2's cooperative barriered epochs (R3's barrier-free per-wave
// streaming was latency-serialized: 380us, HBM 10%). Fixes vs R2 (181us, HBM
// 25%, 2 blocks/CU lockstep drain):
//  - i-tile 32 -> 1024 blocks = 4 blocks/CU; independent phases cover each
//    other's barrier drains.
//  - 2-epoch-deep adj register prefetch (ping-pong st sets): the HBM wait
//    lands in the barrier drain, not mid-epoch before the pack.
//  - one unified bf16 LDS tile layout [32 i][136 shorts] for both halves;
//    !TC writes = conflict-free b128; TC transpose writes = 4-way b32 (cheap);
//    fragment reads bank-uniform.
//  - proj: 3 projections fused into one pass over nodes.

typedef __attribute__((ext_vector_type(8))) short short8;
typedef __attribute__((ext_vector_type(4))) float f32x4;
typedef __attribute__((ext_vector_type(4))) unsigned short u16x4;

#define MFMA(a, b, c) __builtin_amdgcn_mfma_f32_16x16x32_bf16(a, b, c, 0, 0, 0)

__device__ __forceinline__ unsigned short f2bf(float x) {
  union { float f; unsigned u; } v; v.f = x;
  unsigned r = v.u + 0x7FFFu + ((v.u >> 16) & 1u);   // RNE to bf16
  return (unsigned short)(r >> 16);
}

__device__ __forceinline__ short8 pack8(float4 a, float4 b) {
  short8 v;
  v[0] = (short)f2bf(a.x); v[1] = (short)f2bf(a.y); v[2] = (short)f2bf(a.z); v[3] = (short)f2bf(a.w);
  v[4] = (short)f2bf(b.x); v[5] = (short)f2bf(b.y); v[6] = (short)f2bf(b.z); v[7] = (short)f2bf(b.w);
  return v;
}

// ---------------------------------------------------------------------------
// Kernel 1: projections (all three). rep = elu(nodes @ W^T + b).
// grid = 256 blocks x 256 thr; block = 64 nodes; nodes read once.
// ---------------------------------------------------------------------------
__global__ __launch_bounds__(256) void proj_kernel(
    const float* __restrict__ nodes,   // [16384][128]
    const float* __restrict__ W_in, const float* __restrict__ b_in,
    const float* __restrict__ W_out, const float* __restrict__ b_out,
    const float* __restrict__ W_node, const float* __restrict__ b_node,
    unsigned short* __restrict__ in_rep_t,   // [4][128][4096]
    unsigned short* __restrict__ out_rep_t,  // [4][128][4096]
    unsigned short* __restrict__ node_rep)   // [4][4096][128]
{
  const int tid  = threadIdx.x;
  const int lane = tid & 63;
  const int w    = tid >> 6;
  const int q    = lane >> 4;
  const int r15  = lane & 15;
  const int m0   = blockIdx.x * 64 + w * 16;

  short8 a[4];
#pragma unroll
  for (int ks = 0; ks < 4; ++ks) {
    const float* p = nodes + (size_t)(m0 + r15) * 128 + ks * 32 + q * 8;
    a[ks] = pack8(*(const float4*)p, *(const float4*)(p + 4));
  }

  const float* Ws[3]    = { W_in, W_out, W_node };
  const float* biases[3] = { b_in, b_out, b_node };

  for (int wsel = 0; wsel < 3; ++wsel) {
    const float* W    = Ws[wsel];
    const float* bias = biases[wsel];

    f32x4 acc[8];
#pragma unroll
    for (int nt = 0; nt < 8; ++nt) acc[nt] = (f32x4)0.0f;

#pragma unroll
    for (int ks = 0; ks < 4; ++ks)
#pragma unroll
      for (int nt = 0; nt < 8; ++nt) {
        const float* p = W + (size_t)(nt * 16 + r15) * 128 + ks * 32 + q * 8;
        short8 bv = pack8(*(const float4*)p, *(const float4*)(p + 4));
        acc[nt] = MFMA(a[ks], bv, acc[nt]);
      }

#pragma unroll
    for (int nt = 0; nt < 8; ++nt) {
      const int rcol = nt * 16 + r15;
      const float bv = bias[rcol];
      const int g0 = m0 + q * 4;
      float x[4];
#pragma unroll
      for (int c = 0; c < 4; ++c) {
        float t = acc[nt][c] + bv;
        x[c] = (t > 0.f) ? t : (expf(t) - 1.f);   // ELU
      }
      if (wsel < 2) {
        unsigned short* rep = (wsel == 0) ? in_rep_t : out_rep_t;
        const int b = g0 >> 12, j = g0 & 4095;
        u16x4 o;
#pragma unroll
        for (int c = 0; c < 4; ++c) o[c] = f2bf(x[c]);
        *(u16x4*)&rep[((size_t)b << 19) + (size_t)rcol * 4096 + j] = o;
      } else {
#pragma unroll
        for (int c = 0; c < 4; ++c)
          node_rep[(size_t)(g0 + c) * 128 + rcol] = f2bf(x[c]);
      }
    }
  }
}

// ---------------------------------------------------------------------------
// Kernel 2: aggregations. grid = 1024 blocks x 256 thr, interleaved:
//   id&1==0: in_agg[i,v]  = sum_j adj[b][i][j] * in_rep[j][v]
//   id&1==1: out_agg[i,v] = sum_j adj[b][j][i] * out_rep[j][v]   (TC)
// Block tile: 32 i x 128 v; 32 epochs of BK=128 j. LDS: bf16 tile
// [32 i][136 st] x2 buffers (17.4 KB). adj prefetched 2 epochs deep into
// ping-pong register sets. MFMA: A = rep_t[v][j] (global, L2-hot),
// B = LDS tile [i][j]. D: row(m=v)=q*4+reg, col(n=i)=r15 -> 8B agg stores.
// ---------------------------------------------------------------------------
#define AST 136              // shorts per LDS tile row (128 + 8 pad)
#define ABUF (32 * AST)      // one buffer

template <bool TC>
__device__ __forceinline__ void agg_body(
    const float* __restrict__ adjb,
    const unsigned short* __restrict__ rep,
    unsigned short* __restrict__ agg,
    unsigned short* lds, int i0)
{
  const int tid  = threadIdx.x;
  const int lane = tid & 63;
  const int w    = tid >> 6;
  const int q    = lane >> 4;
  const int r15  = lane & 15;

  const unsigned short* arow[2];
#pragma unroll
  for (int mt = 0; mt < 2; ++mt)
    arow[mt] = rep + (size_t)(w * 32 + mt * 16 + r15) * 4096 + q * 8;

  // staging geometry
  int wrow = 0, wcol = 0, tjp = 0, tic = 0;
  const float* ld0; const float* ld1 = nullptr;
  if (!TC) {            // thread: row i=wrow, 16 consecutive j at wcol
    wrow = tid >> 3;                 // 0..31
    wcol = (tid & 7) * 16;           // 0..112
    ld0  = adjb + (size_t)(i0 + wrow) * 4096 + wcol;
  } else {              // thread: rows j=tjp,tjp+1, 8 i at tic
    tjp = (tid >> 2) * 2;            // 0..126 even
    tic = (tid & 3) * 8;             // 0,8,16,24
    ld0 = adjb + (size_t)tjp * 4096 + i0 + tic;
    ld1 = ld0 + 4096;
  }

  float4 st[2][4];   // two epoch-deep prefetch sets
  auto stage_load = [&](int e, float4* s) {
    if (!TC) {
      const float* p = ld0 + e * 128;
#pragma unroll
      for (int i = 0; i < 4; ++i) s[i] = ((const float4*)p)[i];
    } else {
      const float* p0 = ld0 + (size_t)e * 128 * 4096;
      const float* p1 = ld1 + (size_t)e * 128 * 4096;
      s[0] = ((const float4*)p0)[0]; s[1] = ((const float4*)p0)[1];
      s[2] = ((const float4*)p1)[0]; s[3] = ((const float4*)p1)[1];
    }
  };
  auto stage_write = [&](const float4* s, unsigned short* dst) {
    if (!TC) {
      *(short8*)&dst[wrow * AST + wcol]     = pack8(s[0], s[1]);
      *(short8*)&dst[wrow * AST + wcol + 8] = pack8(s[2], s[3]);
    } else {
      const float* r0 = (const float*)&s[0];
      const float* r1 = (const float*)&s[2];
#pragma unroll
      for (int c = 0; c < 8; ++c) {
        unsigned v = (unsigned)f2bf(r0[c]) | ((unsigned)f2bf(r1[c]) << 16);
        *(unsigned*)&dst[(tic + c) * AST + tjp] = v;
      }
    }
  };

  f32x4 acc[2][2];
#pragma unroll
  for (int mt = 0; mt < 2; ++mt)
#pragma unroll
    for (int nt = 0; nt < 2; ++nt) acc[mt][nt] = (f32x4)0.0f;

  // prologue: tile0 -> st[0] -> buf0; tile1 -> st[1]
  stage_load(0, st[0]);
  stage_write(st[0], lds);
  stage_load(1, st[1]);
  __syncthreads();

  for (int e = 0; e < 32; ++e) {
    unsigned short* cur = lds + (e & 1) * ABUF;
    unsigned short* nxt = lds + ((e & 1) ^ 1) * ABUF;

    // A-frags for epoch e (L2-hot rep)
    short8 av[8];
#pragma unroll
    for (int kk = 0; kk < 4; ++kk)
#pragma unroll
      for (int mt = 0; mt < 2; ++mt)
        av[kk * 2 + mt] = *(const short8*)(arow[mt] + e * 128 + kk * 32);

    // prefetch tile e+2 into the set holding tile e (being consumed via LDS)
    if (e < 30) stage_load(e + 2, st[e & 1]);

#pragma unroll
    for (int kk = 0; kk < 4; ++kk)
#pragma unroll
      for (int nt = 0; nt < 2; ++nt) {
        short8 bv = *(const short8*)&cur[(nt * 16 + r15) * AST + kk * 32 + q * 8];
        acc[0][nt] = MFMA(av[kk * 2 + 0], bv, acc[0][nt]);
        acc[1][nt] = MFMA(av[kk * 2 + 1], bv, acc[1][nt]);
      }

    // stage tile e+1 (loaded last epoch, already drained by the barrier)
    if (e < 31) stage_write(st[(e & 1) ^ 1], nxt);
    __syncthreads();
  }

  // epilogue: agg[i][v], 4 consecutive v per lane -> 8B store
#pragma unroll
  for (int mt = 0; mt < 2; ++mt) {
    const int v0 = w * 32 + mt * 16 + q * 4;
#pragma unroll
    for (int nt = 0; nt < 2; ++nt) {
      const int i = i0 + nt * 16 + r15;
      u16x4 o;
#pragma unroll
      for (int c = 0; c < 4; ++c) o[c] = f2bf(acc[mt][nt][c]);
      *(u16x4*)&agg[(size_t)i * 128 + v0] = o;
    }
  }
}

__global__ __launch_bounds__(256, 4) void agg_kernel(
    const float* __restrict__ adj,
    const unsigned short* __restrict__ in_rep_t,
    const unsigned short* __restrict__ out_rep_t,
    unsigned short* __restrict__ in_agg,
    unsigned short* __restrict__ out_agg)
{
  __shared__ unsigned short lds[2 * ABUF];   // 17.4 KB
  const int id   = blockIdx.x;
  const int pass = id & 1;
  const int t    = id >> 1;
  const int b    = t >> 7;
  const int i0   = (t & 127) * 32;
  const float* adjb = adj + ((size_t)b << 24);
  if (pass)
    agg_body<true >(adjb, out_rep_t + ((size_t)b << 19), out_agg + ((size_t)b << 19), lds, i0);
  else
    agg_body<false>(adjb, in_rep_t  + ((size_t)b << 19), in_agg  + ((size_t)b << 19), lds, i0);
}

// ---------------------------------------------------------------------------
// Kernel 3: out[n,o] = tanh(sum_k upd[n,k] * W_upd[o,k] + b_upd[o]),
// upd = concat(in_agg, node_rep, out_agg). grid=512 (n-tile 32).
// ---------------------------------------------------------------------------
__global__ __launch_bounds__(256) void final_kernel(
    const unsigned short* __restrict__ in_agg,    // [16384][128]
    const unsigned short* __restrict__ node_rep,  // [16384][128]
    const unsigned short* __restrict__ out_agg,   // [16384][128]
    const float* __restrict__ W_upd,              // [128][384]
    const float* __restrict__ b_upd,              // [128]
    float* __restrict__ out)                      // [16384][128]
{
  const int tid  = threadIdx.x;
  const int lane = tid & 63;
  const int w    = tid >> 6;
  const int q    = lane >> 4;
  const int r15  = lane & 15;
  const int n0   = blockIdx.x * 32;

  const unsigned short* srcs[3] = { in_agg, node_rep, out_agg };

  f32x4 acc[2][2];
#pragma unroll
  for (int mt = 0; mt < 2; ++mt)
#pragma unroll
    for (int nt = 0; nt < 2; ++nt) acc[mt][nt] = (f32x4)0.0f;

#pragma unroll
  for (int ks = 0; ks < 12; ++ks) {
    const unsigned short* src = srcs[ks >> 2];
    const int col0 = (ks & 3) * 32 + q * 8;
    short8 a[2];
#pragma unroll
    for (int mt = 0; mt < 2; ++mt) {
      const float* p = W_upd + (size_t)(w * 32 + mt * 16 + r15) * 384 + ks * 32 + q * 8;
      a[mt] = pack8(*(const float4*)p, *(const float4*)(p + 4));
    }
#pragma unroll
    for (int nt = 0; nt < 2; ++nt) {
      const int g = n0 + nt * 16 + r15;
      short8 bv = *(const short8*)&src[(size_t)g * 128 + col0];
      acc[0][nt] = MFMA(a[0], bv, acc[0][nt]);
      acc[1][nt] = MFMA(a[1], bv, acc[1][nt]);
    }
  }

#pragma unroll
  for (int mt = 0; mt < 2; ++mt) {
    const int o0 = w * 32 + mt * 16 + q * 4;
#pragma unroll
    for (int nt = 0; nt < 2; ++nt) {
      const int g = n0 + nt * 16 + r15;
      f32x4 ov;
#pragma unroll
      for (int c = 0; c < 4; ++c) ov[c] = tanhf(acc[mt][nt][c] + b_upd[o0 + c]);
      *(f32x4*)&out[(size_t)g * 128 + o0] = ov;
    }
  }
}

// ---------------------------------------------------------------------------
extern "C" void kernel_launch(void* const* d_in, const int* in_sizes, int n_in,
                              void* d_out, int out_size, void* d_ws, size_t ws_size,
                              hipStream_t stream) {
  (void)in_sizes; (void)n_in; (void)out_size; (void)ws_size;
  const float* nodes  = (const float*)d_in[0];
  const float* adj    = (const float*)d_in[1];
  const float* W_in   = (const float*)d_in[2];
  const float* b_in   = (const float*)d_in[3];
  const float* W_out  = (const float*)d_in[4];
  const float* b_out  = (const float*)d_in[5];
  const float* W_node = (const float*)d_in[6];
  const float* b_node = (const float*)d_in[7];
  const float* W_upd  = (const float*)d_in[8];
  const float* b_upd  = (const float*)d_in[9];
  float* out = (float*)d_out;

  unsigned short* ws = (unsigned short*)d_ws;
  const size_t SZ = (size_t)4 * 128 * 4096;
  unsigned short* in_rep_t  = ws;
  unsigned short* out_rep_t = ws + SZ;
  unsigned short* node_rep  = ws + 2 * SZ;
  unsigned short* in_agg    = ws + 3 * SZ;
  unsigned short* out_agg   = ws + 4 * SZ;

  proj_kernel<<<256, 256, 0, stream>>>(
      nodes, W_in, b_in, W_out, b_out, W_node, b_node,
      in_rep_t, out_rep_t, node_rep);
  agg_kernel<<<1024, 256, 0, stream>>>(adj, in_rep_t, out_rep_t, in_agg, out_agg);
  final_kernel<<<512, 256, 0, stream>>>(in_agg, node_rep, out_agg, W_upd, b_upd, out);
}

// Round 5
// 563.530 us; speedup vs baseline: 1.2489x; 1.2489x over previous
//
#include <hip/hip_runtime.h>
#include <hip/hip_bf16.h>

// GraphSageLayer on MI355X. B=4, N=4096, D_IN=REP=D_OUT=128.
// proj (nodes->3 reps, bf16) -> agg (adj @ in_rep, adj^T @ out_rep) -> final (concat @ W_upd^T, tanh).
//
// R5 = R4 with the scratch-spill fixed. R4 evidence: WRITE_SIZE 8MB -> 442MB,
// VGPR 64, MfmaUtil 3.9% -- `float4 st[2][4]` indexed by st[e&1] in a rolled
// loop went to scratch; every thread round-tripped 64B/epoch through HBM
// (~500MB). Fix: hand-unroll the epoch loop x2 with named register sets
// st0/st1 (all indices compile-time). Structure otherwise identical to R4:
// 1024 blocks (4/CU), 32i x 128v tile, BK=128 epochs, 2-epoch-deep adj
// register prefetch, unified bf16 LDS tile [32][136] x2.

typedef __attribute__((ext_vector_type(8))) short short8;
typedef __attribute__((ext_vector_type(4))) float f32x4;
typedef __attribute__((ext_vector_type(4))) unsigned short u16x4;

#define MFMA(a, b, c) __builtin_amdgcn_mfma_f32_16x16x32_bf16(a, b, c, 0, 0, 0)

__device__ __forceinline__ unsigned short f2bf(float x) {
  union { float f; unsigned u; } v; v.f = x;
  unsigned r = v.u + 0x7FFFu + ((v.u >> 16) & 1u);   // RNE to bf16
  return (unsigned short)(r >> 16);
}

__device__ __forceinline__ short8 pack8(float4 a, float4 b) {
  short8 v;
  v[0] = (short)f2bf(a.x); v[1] = (short)f2bf(a.y); v[2] = (short)f2bf(a.z); v[3] = (short)f2bf(a.w);
  v[4] = (short)f2bf(b.x); v[5] = (short)f2bf(b.y); v[6] = (short)f2bf(b.z); v[7] = (short)f2bf(b.w);
  return v;
}

// ---------------------------------------------------------------------------
// Kernel 1: projections (all three). rep = elu(nodes @ W^T + b).
// grid = 256 blocks x 256 thr; block = 64 nodes; nodes read once.
// ---------------------------------------------------------------------------
__global__ __launch_bounds__(256) void proj_kernel(
    const float* __restrict__ nodes,   // [16384][128]
    const float* __restrict__ W_in, const float* __restrict__ b_in,
    const float* __restrict__ W_out, const float* __restrict__ b_out,
    const float* __restrict__ W_node, const float* __restrict__ b_node,
    unsigned short* __restrict__ in_rep_t,   // [4][128][4096]
    unsigned short* __restrict__ out_rep_t,  // [4][128][4096]
    unsigned short* __restrict__ node_rep)   // [4][4096][128]
{
  const int tid  = threadIdx.x;
  const int lane = tid & 63;
  const int w    = tid >> 6;
  const int q    = lane >> 4;
  const int r15  = lane & 15;
  const int m0   = blockIdx.x * 64 + w * 16;

  short8 a[4];
#pragma unroll
  for (int ks = 0; ks < 4; ++ks) {
    const float* p = nodes + (size_t)(m0 + r15) * 128 + ks * 32 + q * 8;
    a[ks] = pack8(*(const float4*)p, *(const float4*)(p + 4));
  }

  const float* Ws[3]     = { W_in, W_out, W_node };
  const float* biases[3] = { b_in, b_out, b_node };

  for (int wsel = 0; wsel < 3; ++wsel) {
    const float* W    = Ws[wsel];
    const float* bias = biases[wsel];

    f32x4 acc[8];
#pragma unroll
    for (int nt = 0; nt < 8; ++nt) acc[nt] = (f32x4)0.0f;

#pragma unroll
    for (int ks = 0; ks < 4; ++ks)
#pragma unroll
      for (int nt = 0; nt < 8; ++nt) {
        const float* p = W + (size_t)(nt * 16 + r15) * 128 + ks * 32 + q * 8;
        short8 bv = pack8(*(const float4*)p, *(const float4*)(p + 4));
        acc[nt] = MFMA(a[ks], bv, acc[nt]);
      }

#pragma unroll
    for (int nt = 0; nt < 8; ++nt) {
      const int rcol = nt * 16 + r15;
      const float bv = bias[rcol];
      const int g0 = m0 + q * 4;
      float x[4];
#pragma unroll
      for (int c = 0; c < 4; ++c) {
        float t = acc[nt][c] + bv;
        x[c] = (t > 0.f) ? t : (expf(t) - 1.f);   // ELU
      }
      if (wsel < 2) {
        unsigned short* rep = (wsel == 0) ? in_rep_t : out_rep_t;
        const int b = g0 >> 12, j = g0 & 4095;
        u16x4 o;
#pragma unroll
        for (int c = 0; c < 4; ++c) o[c] = f2bf(x[c]);
        *(u16x4*)&rep[((size_t)b << 19) + (size_t)rcol * 4096 + j] = o;
      } else {
#pragma unroll
        for (int c = 0; c < 4; ++c)
          node_rep[(size_t)(g0 + c) * 128 + rcol] = f2bf(x[c]);
      }
    }
  }
}

// ---------------------------------------------------------------------------
// Kernel 2: aggregations. grid = 1024 blocks x 256 thr, interleaved:
//   id&1==0: in_agg[i,v]  = sum_j adj[b][i][j] * in_rep[j][v]
//   id&1==1: out_agg[i,v] = sum_j adj[b][j][i] * out_rep[j][v]   (TC)
// Block tile: 32 i x 128 v; 32 epochs of BK=128 j. LDS bf16 tile
// [32 i][136 st] x2 (17.4 KB). adj prefetched 2 epochs deep into NAMED
// register sets st0/st1 (epoch loop hand-unrolled x2 -> no scratch).
// ---------------------------------------------------------------------------
#define AST 136              // shorts per LDS tile row (128 + 8 pad)
#define ABUF (32 * AST)      // one buffer

template <bool TC>
__device__ __forceinline__ void agg_body(
    const float* __restrict__ adjb,
    const unsigned short* __restrict__ rep,
    unsigned short* __restrict__ agg,
    unsigned short* lds, int i0)
{
  const int tid  = threadIdx.x;
  const int lane = tid & 63;
  const int w    = tid >> 6;
  const int q    = lane >> 4;
  const int r15  = lane & 15;

  const unsigned short* arow[2];
#pragma unroll
  for (int mt = 0; mt < 2; ++mt)
    arow[mt] = rep + (size_t)(w * 32 + mt * 16 + r15) * 4096 + q * 8;

  // staging geometry
  int wrow = 0, wcol = 0, tjp = 0, tic = 0;
  const float* ld0; const float* ld1 = nullptr;
  if (!TC) {            // thread: row i=wrow, 16 consecutive j at wcol
    wrow = tid >> 3;                 // 0..31
    wcol = (tid & 7) * 16;           // 0..112
    ld0  = adjb + (size_t)(i0 + wrow) * 4096 + wcol;
  } else {              // thread: rows j=tjp,tjp+1, 8 i at tic
    tjp = (tid >> 2) * 2;            // 0..126 even
    tic = (tid & 3) * 8;             // 0,8,16,24
    ld0 = adjb + (size_t)tjp * 4096 + i0 + tic;
    ld1 = ld0 + 4096;
  }

  float4 st0[4], st1[4];   // 2-epoch prefetch, NAMED sets (registers)

  auto stage_load = [&](int e, float4* s) {
    if (!TC) {
      const float* p = ld0 + e * 128;
#pragma unroll
      for (int i = 0; i < 4; ++i) s[i] = ((const float4*)p)[i];
    } else {
      const float* p0 = ld0 + (size_t)e * 128 * 4096;
      const float* p1 = ld1 + (size_t)e * 128 * 4096;
      s[0] = ((const float4*)p0)[0]; s[1] = ((const float4*)p0)[1];
      s[2] = ((const float4*)p1)[0]; s[3] = ((const float4*)p1)[1];
    }
  };
  auto stage_write = [&](const float4* s, unsigned short* dst) {
    if (!TC) {
      *(short8*)&dst[wrow * AST + wcol]     = pack8(s[0], s[1]);
      *(short8*)&dst[wrow * AST + wcol + 8] = pack8(s[2], s[3]);
    } else {
      const float* r0 = (const float*)&s[0];
      const float* r1 = (const float*)&s[2];
#pragma unroll
      for (int c = 0; c < 8; ++c) {
        unsigned v = (unsigned)f2bf(r0[c]) | ((unsigned)f2bf(r1[c]) << 16);
        *(unsigned*)&dst[(tic + c) * AST + tjp] = v;
      }
    }
  };

  f32x4 acc[2][2];
#pragma unroll
  for (int mt = 0; mt < 2; ++mt)
#pragma unroll
    for (int nt = 0; nt < 2; ++nt) acc[mt][nt] = (f32x4)0.0f;

  // one epoch body; parity and guards are compile-time per call site below
  auto epoch = [&](int e, unsigned short* cur, unsigned short* nxt,
                   float4* s_load, float4* s_write, bool do_load, bool do_write) {
    short8 av[8];
#pragma unroll
    for (int kk = 0; kk < 4; ++kk)
#pragma unroll
      for (int mt = 0; mt < 2; ++mt)
        av[kk * 2 + mt] = *(const short8*)(arow[mt] + e * 128 + kk * 32);

    if (do_load) stage_load(e + 2, s_load);

#pragma unroll
    for (int kk = 0; kk < 4; ++kk)
#pragma unroll
      for (int nt = 0; nt < 2; ++nt) {
        short8 bv = *(const short8*)&cur[(nt * 16 + r15) * AST + kk * 32 + q * 8];
        acc[0][nt] = MFMA(av[kk * 2 + 0], bv, acc[0][nt]);
        acc[1][nt] = MFMA(av[kk * 2 + 1], bv, acc[1][nt]);
      }

    if (do_write) stage_write(s_write, nxt);
    __syncthreads();
  };

  // prologue: tile0 -> st0 -> buf0; tile1 -> st1
  stage_load(0, st0);
  stage_write(st0, lds);
  stage_load(1, st1);
  __syncthreads();

  for (int e = 0; e < 32; e += 2) {
    // even epoch: consume buf0; load tile e+2 -> st0; stage tile e+1 (st1) -> buf1
    epoch(e,     lds,        lds + ABUF, st0, st1, e < 30, true);
    // odd epoch: consume buf1; load tile e+3 -> st1; stage tile e+2 (st0) -> buf0
    epoch(e + 1, lds + ABUF, lds,        st1, st0, e + 1 < 30, e + 1 < 31);
  }

  // epilogue: agg[i][v], 4 consecutive v per lane -> 8B store
#pragma unroll
  for (int mt = 0; mt < 2; ++mt) {
    const int v0 = w * 32 + mt * 16 + q * 4;
#pragma unroll
    for (int nt = 0; nt < 2; ++nt) {
      const int i = i0 + nt * 16 + r15;
      u16x4 o;
#pragma unroll
      for (int c = 0; c < 4; ++c) o[c] = f2bf(acc[mt][nt][c]);
      *(u16x4*)&agg[(size_t)i * 128 + v0] = o;
    }
  }
}

__global__ __launch_bounds__(256, 4) void agg_kernel(
    const float* __restrict__ adj,
    const unsigned short* __restrict__ in_rep_t,
    const unsigned short* __restrict__ out_rep_t,
    unsigned short* __restrict__ in_agg,
    unsigned short* __restrict__ out_agg)
{
  __shared__ unsigned short lds[2 * ABUF];   // 17.4 KB
  const int id   = blockIdx.x;
  const int pass = id & 1;
  const int t    = id >> 1;
  const int b    = t >> 7;
  const int i0   = (t & 127) * 32;
  const float* adjb = adj + ((size_t)b << 24);
  if (pass)
    agg_body<true >(adjb, out_rep_t + ((size_t)b << 19), out_agg + ((size_t)b << 19), lds, i0);
  else
    agg_body<false>(adjb, in_rep_t  + ((size_t)b << 19), in_agg  + ((size_t)b << 19), lds, i0);
}

// ---------------------------------------------------------------------------
// Kernel 3: out[n,o] = tanh(sum_k upd[n,k] * W_upd[o,k] + b_upd[o]),
// upd = concat(in_agg, node_rep, out_agg). grid=512 (n-tile 32).
// ---------------------------------------------------------------------------
__global__ __launch_bounds__(256) void final_kernel(
    const unsigned short* __restrict__ in_agg,    // [16384][128]
    const unsigned short* __restrict__ node_rep,  // [16384][128]
    const unsigned short* __restrict__ out_agg,   // [16384][128]
    const float* __restrict__ W_upd,              // [128][384]
    const float* __restrict__ b_upd,              // [128]
    float* __restrict__ out)                      // [16384][128]
{
  const int tid  = threadIdx.x;
  const int lane = tid & 63;
  const int w    = tid >> 6;
  const int q    = lane >> 4;
  const int r15  = lane & 15;
  const int n0   = blockIdx.x * 32;

  const unsigned short* srcs[3] = { in_agg, node_rep, out_agg };

  f32x4 acc[2][2];
#pragma unroll
  for (int mt = 0; mt < 2; ++mt)
#pragma unroll
    for (int nt = 0; nt < 2; ++nt) acc[mt][nt] = (f32x4)0.0f;

#pragma unroll
  for (int ks = 0; ks < 12; ++ks) {
    const unsigned short* src = srcs[ks >> 2];
    const int col0 = (ks & 3) * 32 + q * 8;
    short8 a[2];
#pragma unroll
    for (int mt = 0; mt < 2; ++mt) {
      const float* p = W_upd + (size_t)(w * 32 + mt * 16 + r15) * 384 + ks * 32 + q * 8;
      a[mt] = pack8(*(const float4*)p, *(const float4*)(p + 4));
    }
#pragma unroll
    for (int nt = 0; nt < 2; ++nt) {
      const int g = n0 + nt * 16 + r15;
      short8 bv = *(const short8*)&src[(size_t)g * 128 + col0];
      acc[0][nt] = MFMA(a[0], bv, acc[0][nt]);
      acc[1][nt] = MFMA(a[1], bv, acc[1][nt]);
    }
  }

#pragma unroll
  for (int mt = 0; mt < 2; ++mt) {
    const int o0 = w * 32 + mt * 16 + q * 4;
#pragma unroll
    for (int nt = 0; nt < 2; ++nt) {
      const int g = n0 + nt * 16 + r15;
      f32x4 ov;
#pragma unroll
      for (int c = 0; c < 4; ++c) ov[c] = tanhf(acc[mt][nt][c] + b_upd[o0 + c]);
      *(f32x4*)&out[(size_t)g * 128 + o0] = ov;
    }
  }
}

// ---------------------------------------------------------------------------
extern "C" void kernel_launch(void* const* d_in, const int* in_sizes, int n_in,
                              void* d_out, int out_size, void* d_ws, size_t ws_size,
                              hipStream_t stream) {
  (void)in_sizes; (void)n_in; (void)out_size; (void)ws_size;
  const float* nodes  = (const float*)d_in[0];
  const float* adj    = (const float*)d_in[1];
  const float* W_in   = (const float*)d_in[2];
  const float* b_in   = (const float*)d_in[3];
  const float* W_out  = (const float*)d_in[4];
  const float* b_out  = (const float*)d_in[5];
  const float* W_node = (const float*)d_in[6];
  const float* b_node = (const float*)d_in[7];
  const float* W_upd  = (const float*)d_in[8];
  const float* b_upd  = (const float*)d_in[9];
  float* out = (float*)d_out;

  unsigned short* ws = (unsigned short*)d_ws;
  const size_t SZ = (size_t)4 * 128 * 4096;
  unsigned short* in_rep_t  = ws;
  unsigned short* out_rep_t = ws + SZ;
  unsigned short* node_rep  = ws + 2 * SZ;
  unsigned short* in_agg    = ws + 3 * SZ;
  unsigned short* out_agg   = ws + 4 * SZ;

  proj_kernel<<<256, 256, 0, stream>>>(
      nodes, W_in, b_in, W_out, b_out, W_node, b_node,
      in_rep_t, out_rep_t, node_rep);
  agg_kernel<<<1024, 256, 0, stream>>>(adj, in_rep_t, out_rep_t, in_agg, out_agg);
  final_kernel<<<512, 256, 0, stream>>>(in_agg, node_rep, out_agg, W_upd, b_upd, out);
}